// Round 3
// baseline (313.155 us; speedup 1.0000x reference)
//
#include <hip/hip_runtime.h>
#include <math.h>

#define FFT_N 16384
#define MASK (FFT_N - 1)
#define NT 1024
#define RPT 16
#define B_DIM 8
#define H_DIM 256

// XOR swizzle on float2 index: spreads bank-pairs for the nC/nD patterns,
// harmless (constant-per-wave xor) for nA/nB. Bijective on [0,16384).
#define SWF(f) ((f) ^ (((f) >> 6) & 15))

__device__ __forceinline__ float2 cmul(float2 a, float2 b) {
    return make_float2(a.x * b.x - a.y * b.y, a.x * b.y + a.y * b.x);
}
__device__ __forceinline__ float2 cadd(float2 a, float2 b) { return make_float2(a.x + b.x, a.y + b.y); }
__device__ __forceinline__ float2 csub(float2 a, float2 b) { return make_float2(a.x - b.x, a.y - b.y); }
__device__ __forceinline__ float2 mulnegi(float2 z) { return make_float2(z.y, -z.x); }   // -i*z
__device__ __forceinline__ float2 mulposi(float2 z) { return make_float2(-z.y, z.x); }   // +i*z

// ---- radix-4 butterflies (same algebra as verified R1/R2; w2,w3 now table-loaded) ----
__device__ __forceinline__ void bfly4(float2& a, float2& b, float2& c, float2& d,
                                      float2 w1, float2 w2, float2 w3) {
    float2 apc = cadd(a, c), amc = csub(a, c);
    float2 bpd = cadd(b, d), bmd = csub(b, d);
    float2 nib = mulnegi(bmd);
    a = cadd(apc, bpd);
    b = cmul(csub(apc, bpd), w2);
    c = cmul(cadd(amc, nib), w1);
    d = cmul(csub(amc, nib), w3);
}
__device__ __forceinline__ void bfly4_nw(float2& a, float2& b, float2& c, float2& d) {
    float2 apc = cadd(a, c), amc = csub(a, c);
    float2 bpd = cadd(b, d), bmd = csub(b, d);
    float2 nib = mulnegi(bmd);
    a = cadd(apc, bpd);
    b = csub(apc, bpd);
    c = cadd(amc, nib);
    d = csub(amc, nib);
}
// inverse DIT butterfly: w1t=tw[i], w2t=tw[2i]; conj applied inside (== R2's w1=conj, w2=w1^2)
__device__ __forceinline__ void ibfly4(float2& a, float2& b, float2& c, float2& d,
                                       float2 w1t, float2 w2t) {
    float2 w1 = make_float2(w1t.x, -w1t.y);
    float2 w2 = make_float2(w2t.x, -w2t.y);
    float2 bt = cmul(b, w2), dt = cmul(d, w2);
    float2 A = cadd(a, bt), Bb = csub(a, bt);
    float2 C = cadd(c, dt), Dd = csub(c, dt);
    float2 Cw = cmul(C, w1);
    float2 Dw = mulposi(cmul(Dd, w1));
    a = cadd(A, Cw);  c = csub(A, Cw);
    b = cadd(Bb, Dw); d = csub(Bb, Dw);
}
__device__ __forceinline__ void ibfly4_nw(float2& a, float2& b, float2& c, float2& d) {
    float2 A = cadd(a, b), Bb = csub(a, b);
    float2 C = cadd(c, d), Dd = csub(c, d);
    float2 Dw = mulposi(Dd);
    a = cadd(A, C);  c = csub(A, C);
    b = cadd(Bb, Dw); d = csub(Bb, Dw);
}

// ---- register phases: two radix-4 stages on r[16] (radix-16) ----
// stage s twiddle for group position t_pos is tw[t_pos * 4^s]; here i=(lp+P*j0)*ST.
// Second stage's t_pos == lp for all quads -> uniform twiddle (1 load).
template<int P, int ST>
__device__ __forceinline__ void fwd_phase16(float2 r[RPT], int lp, const float2* __restrict__ tw) {
#pragma unroll
    for (int j0 = 0; j0 < 4; ++j0) {
        const int i = (lp + P * j0) * ST;
        bfly4(r[j0], r[j0 + 4], r[j0 + 8], r[j0 + 12],
              tw[i & MASK], tw[(2 * i) & MASK], tw[(3 * i) & MASK]);
    }
    {
        const int i = lp * (ST * 4);
        const float2 w1 = tw[i & MASK], w2 = tw[(2 * i) & MASK], w3 = tw[(3 * i) & MASK];
#pragma unroll
        for (int a = 0; a < 4; ++a)
            bfly4(r[4 * a], r[4 * a + 1], r[4 * a + 2], r[4 * a + 3], w1, w2, w3);
    }
}
template<int P, int ST>
__device__ __forceinline__ void inv_phase16(float2 r[RPT], int lp, const float2* __restrict__ tw) {
    {
        const int i = lp * (ST * 4);
        const float2 w1 = tw[i & MASK], w2 = tw[(2 * i) & MASK];
#pragma unroll
        for (int a = 0; a < 4; ++a)
            ibfly4(r[4 * a], r[4 * a + 1], r[4 * a + 2], r[4 * a + 3], w1, w2);
    }
#pragma unroll
    for (int j0 = 0; j0 < 4; ++j0) {
        const int i = (lp + P * j0) * ST;
        ibfly4(r[j0], r[j0 + 4], r[j0 + 8], r[j0 + 12], tw[i & MASK], tw[(2 * i) & MASK]);
    }
}
__device__ __forceinline__ void fwd_phaseD16(float2 r[RPT]) {
#pragma unroll
    for (int a = 0; a < 4; ++a)
        bfly4_nw(r[4 * a], r[4 * a + 1], r[4 * a + 2], r[4 * a + 3]);
}
__device__ __forceinline__ void inv_phaseD16(float2 r[RPT]) {
#pragma unroll
    for (int a = 0; a < 4; ++a)
        ibfly4_nw(r[4 * a], r[4 * a + 1], r[4 * a + 2], r[4 * a + 3]);
}

// ---- element index owned by thread t, slot j, per phase ----
#define nA(t, j) ((t) + NT * (j))                                  // stages 0,1 (strides 4096,1024)
#define nB(t, j) ((((t) >> 6) << 10) + ((t) & 63) + 64 * (j))      // stages 2,3 (256,64)
#define nC(t, j) ((((t) >> 2) << 6) + ((t) & 3) + 4 * (j))         // stages 4,5 (16,4)
#define nD(t, j) (16 * (t) + (j))                                  // stage 6 (1)

#define EXCHANGE(NFROM, NTO)                                           \
    do {                                                               \
        _Pragma("unroll") for (int j = 0; j < RPT; ++j)                \
            lds2[SWF(NFROM(t, j))] = r[j];                             \
        __syncthreads();                                               \
        _Pragma("unroll") for (int j = 0; j < RPT; ++j)                \
            r[j] = lds2[SWF(NTO(t, j))];                               \
        __syncthreads();                                               \
    } while (0)

__device__ __forceinline__ float ftanh(float x) {
    // tanh(x) = 1 - 2/(e^{2x}+1); exact saturation at +-1 for large |x|
    float e = __expf(2.0f * x);
    return 1.0f - 2.0f * __builtin_amdgcn_rcpf(e + 1.0f);
}

__global__ void twiddle_init(float2* __restrict__ tw) {
    int t = blockIdx.x * blockDim.x + threadIdx.x;
    if (t < FFT_N) {
        float ang = -2.0f * 3.14159265358979323846f * (float)t / (float)FFT_N;
        float sv, cv;
        sincosf(ang, &sv, &cv);
        tw[t] = make_float2(cv, sv);
    }
}

// Forward FFT of (k_h + dh*delta) -> Kf[h] in DIF storage order.
// diag(D) feedthrough folded in exactly: conv(u,k)+dh*u == conv(u, k+dh*delta).
__global__ __launch_bounds__(NT, 4) void kfft_kernel(const float* __restrict__ k,
                                                     const float* __restrict__ D,
                                                     const float2* __restrict__ tw,
                                                     float2* __restrict__ Kf) {
    __shared__ float2 lds2[FFT_N];
    const int h = blockIdx.x;
    const int t = threadIdx.x;
    const float* krow = k + (size_t)h * FFT_N;
    float2 r[RPT];
#pragma unroll
    for (int j = 0; j < RPT; ++j) r[j] = make_float2(krow[nA(t, j)], 0.f);
    if (t == 0) r[0].x += D[h * (H_DIM + 1)];
    fwd_phase16<NT, 1>(r, t, tw);
    EXCHANGE(nA, nB);
    fwd_phase16<64, 16>(r, t & 63, tw);
    EXCHANGE(nB, nC);
    fwd_phase16<4, 256>(r, t & 3, tw);
    EXCHANGE(nC, nD);
    fwd_phaseD16(r);
    float2* outr = Kf + (size_t)h * FFT_N;
#pragma unroll
    for (int j = 0; j < RPT; ++j) outr[nD(t, j)] = r[j];
}

// Batch rows (2p,h) and (2p+1,h) packed as z = u0 + i*u1 (conv is linear, k real).
__global__ __launch_bounds__(NT, 4) void conv_kernel(const float* __restrict__ u,
                                                     const float2* __restrict__ tw,
                                                     const float2* __restrict__ Kf,
                                                     float* __restrict__ out) {
    __shared__ float2 lds2[FFT_N];
    // XCD-chunked bijection (1024 % 8 == 0): the 4 blocks sharing h land on one XCD
    const int raw = blockIdx.x;
    const int vb = ((raw & 7) << 7) + (raw >> 3);
    const int h = vb >> 2;
    const int p = vb & 3;
    const int t = threadIdx.x;
    const size_t row0 = ((size_t)(2 * p) * H_DIM + h) * FFT_N;
    const size_t row1 = row0 + (size_t)H_DIM * FFT_N;
    const float* u0 = u + row0;
    const float* u1 = u + row1;

    float2 r[RPT];
#pragma unroll
    for (int j = 0; j < RPT; ++j) {
        const int n = nA(t, j);
        r[j] = make_float2(u0[n], u1[n]);
    }

    fwd_phase16<NT, 1>(r, t, tw);
    EXCHANGE(nA, nB);
    fwd_phase16<64, 16>(r, t & 63, tw);
    EXCHANGE(nB, nC);
    fwd_phase16<4, 256>(r, t & 3, tw);
    EXCHANGE(nC, nD);
    fwd_phaseD16(r);

    // pointwise multiply in digit-reversed storage order (matches kfft) + 1/N
    {
        const float2* kfrow = Kf + (size_t)h * FFT_N;
        const float invN = 1.0f / (float)FFT_N;
#pragma unroll
        for (int j = 0; j < RPT; ++j) {
            const float2 w = kfrow[nD(t, j)];
            const float2 z = r[j];
            r[j] = make_float2((z.x * w.x - z.y * w.y) * invN,
                               (z.x * w.y + z.y * w.x) * invN);
        }
    }

    inv_phaseD16(r);
    EXCHANGE(nD, nC);
    inv_phase16<4, 256>(r, t & 3, tw);
    EXCHANGE(nC, nB);
    inv_phase16<64, 16>(r, t & 63, tw);
    EXCHANGE(nB, nA);
    inv_phase16<NT, 1>(r, t, tw);

    float* o0 = out + row0;
    float* o1 = out + row1;
#pragma unroll
    for (int j = 0; j < RPT; ++j) {
        const int n = nA(t, j);
        o0[n] = ftanh(r[j].x);
        o1[n] = ftanh(r[j].y);
    }
}

extern "C" void kernel_launch(void* const* d_in, const int* in_sizes, int n_in,
                              void* d_out, int out_size, void* d_ws, size_t ws_size,
                              hipStream_t stream) {
    const float* u = (const float*)d_in[0];   // (B,H,L) f32
    const float* k = (const float*)d_in[1];   // (H,L)   f32
    const float* D = (const float*)d_in[2];   // (H,H)   f32
    float* out = (float*)d_out;

    float2* tw = (float2*)d_ws;               // 16384 float2 = 128 KiB
    float2* Kf = tw + FFT_N;                  // 256*16384 float2 = 32 MiB

    twiddle_init<<<FFT_N / 256, 256, 0, stream>>>(tw);
    kfft_kernel<<<H_DIM, NT, 0, stream>>>(k, D, tw, Kf);
    conv_kernel<<<(B_DIM / 2) * H_DIM, NT, 0, stream>>>(u, tw, Kf, out);
}